// Round 5
// baseline (55.598 us; speedup 1.0000x reference)
//
#include <hip/hip_runtime.h>

#define B_    4
#define N_    1024
#define L_    8
#define FV_   64
#define OUT_  8
#define INFEAT_ (L_ + 2*FV_)   // 136

typedef float f32x4 __attribute__((ext_vector_type(4)));

// Kernel 1: thread -> (pair = b*N+j, o). 8 consecutive threads share one V row.
// tv1[b][o][j] = sum_f V[b,j,f]*W[o, L+f]
// tv2[b][j][o] = sum_f V[b,j,f]*W[o, L+FV+f]
__global__ __launch_bounds__(256) void precompute_tv_kernel(
    const float* __restrict__ V, const float* __restrict__ W,
    float* __restrict__ tv1, float* __restrict__ tv2)
{
    __shared__ float wv[2][OUT_][FV_];   // 4 KB
    for (int k = threadIdx.x; k < OUT_ * FV_; k += 256) {
        int o = k >> 6, f = k & 63;
        wv[0][o][f] = W[o * INFEAT_ + L_ + f];
        wv[1][o][f] = W[o * INFEAT_ + L_ + FV_ + f];
    }
    __syncthreads();

    int gt   = blockIdx.x * 256 + threadIdx.x;   // 0 .. 32767
    int pair = gt >> 3;                          // 0 .. B*N-1
    int o    = gt & 7;
    int b    = pair >> 10;
    int j    = pair & 1023;

    const float* vrow = V + (size_t)pair * FV_;

    float s1 = 0.f, s2 = 0.f;
    #pragma unroll
    for (int f = 0; f < FV_; f += 4) {
        f32x4 x = *reinterpret_cast<const f32x4*>(vrow + f);
        s1 += x.x * wv[0][o][f]     + x.y * wv[0][o][f + 1]
            + x.z * wv[0][o][f + 2] + x.w * wv[0][o][f + 3];
        s2 += x.x * wv[1][o][f]     + x.y * wv[1][o][f + 1]
            + x.z * wv[1][o][f + 2] + x.w * wv[1][o][f + 3];
    }
    tv1[(b * OUT_ + o) * N_ + j] = s1;
    tv2[(size_t)pair * OUT_ + o] = s2;
}

// Kernel 2: one block per (b,i). NO LDS, NO barrier — all weight/bias/tv2
// accesses are wave-uniform -> compiler emits scalar (SMEM) loads into SGPRs,
// so the streaming A loads issue immediately at wave start.
// out[b,i,o,j] = relu( sum_l A[b,i,l,j]*W[o,l] + tv1[b,o,j] + tv2[b,i,o] + bias[o] )
__global__ __launch_bounds__(256) void graphcnn_main_kernel(
    const float* __restrict__ A, const float* __restrict__ W,
    const float* __restrict__ bias,
    const float* __restrict__ tv1, const float* __restrict__ tv2,
    float* __restrict__ out)
{
    int bi = blockIdx.x;          // b*N + i
    int b  = bi >> 10;
    int t  = threadIdx.x;
    int j  = t * 4;               // 256 threads * 4 = 1024 = N

    const float* arow = A + (size_t)bi * (L_ * N_);
    const float* tv1b = tv1 + b * OUT_ * N_;
    float* orow = out + (size_t)bi * (OUT_ * N_);

    // 8 streaming A loads (non-temporal), hoisted: needed by every o.
    f32x4 a[L_];
    #pragma unroll
    for (int l = 0; l < L_; ++l)
        a[l] = __builtin_nontemporal_load(
                   reinterpret_cast<const f32x4*>(arow + l * N_ + j));

    #pragma unroll
    for (int o = 0; o < OUT_; ++o) {
        // Wave-uniform scalar values (SGPR): bias[o] + tv2[bi*8+o]
        float bo = bias[o] + tv2[(size_t)bi * OUT_ + o];
        f32x4 r = *reinterpret_cast<const f32x4*>(tv1b + o * N_ + j);
        r.x += bo; r.y += bo; r.z += bo; r.w += bo;
        #pragma unroll
        for (int l = 0; l < L_; ++l) {
            float w = W[o * INFEAT_ + l];   // wave-uniform -> SGPR
            r.x = fmaf(a[l].x, w, r.x);
            r.y = fmaf(a[l].y, w, r.y);
            r.z = fmaf(a[l].z, w, r.z);
            r.w = fmaf(a[l].w, w, r.w);
        }
        r.x = fmaxf(r.x, 0.f);
        r.y = fmaxf(r.y, 0.f);
        r.z = fmaxf(r.z, 0.f);
        r.w = fmaxf(r.w, 0.f);
        __builtin_nontemporal_store(r, reinterpret_cast<f32x4*>(orow + o * N_ + j));
    }
}

extern "C" void kernel_launch(void* const* d_in, const int* in_sizes, int n_in,
                              void* d_out, int out_size, void* d_ws, size_t ws_size,
                              hipStream_t stream) {
    const float* A    = (const float*)d_in[0];
    const float* V    = (const float*)d_in[1];
    const float* W    = (const float*)d_in[2];
    const float* bias = (const float*)d_in[3];
    float* out = (float*)d_out;

    float* tv1 = (float*)d_ws;                    // B*OUT*N floats = 32768
    float* tv2 = tv1 + (size_t)B_ * OUT_ * N_;    // B*N*OUT floats = 32768

    precompute_tv_kernel<<<(B_ * N_ * OUT_) / 256, 256, 0, stream>>>(V, W, tv1, tv2);
    graphcnn_main_kernel<<<B_ * N_, 256, 0, stream>>>(A, W, bias, tv1, tv2, out);
}

// Round 6
// 52.497 us; speedup vs baseline: 1.0591x; 1.0591x over previous
//
#include <hip/hip_runtime.h>

#define B_    4
#define N_    1024
#define L_    8
#define FV_   64
#define OUT_  8
#define INFEAT_ (L_ + 2*FV_)   // 136

typedef float f32x4 __attribute__((ext_vector_type(4)));

// Kernel 1: thread -> (pair = b*N+j, o). 8 consecutive threads share one V row.
// tv1[b][o][j] = sum_f V[b,j,f]*W[o, L+f]
// tv2[b][j][o] = sum_f V[b,j,f]*W[o, L+FV+f]
__global__ __launch_bounds__(256) void precompute_tv_kernel(
    const float* __restrict__ V, const float* __restrict__ W,
    float* __restrict__ tv1, float* __restrict__ tv2)
{
    __shared__ float wv[2][OUT_][FV_];   // 4 KB
    for (int k = threadIdx.x; k < OUT_ * FV_; k += 256) {
        int o = k >> 6, f = k & 63;
        wv[0][o][f] = W[o * INFEAT_ + L_ + f];
        wv[1][o][f] = W[o * INFEAT_ + L_ + FV_ + f];
    }
    __syncthreads();

    int gt   = blockIdx.x * 256 + threadIdx.x;   // 0 .. 32767
    int pair = gt >> 3;                          // 0 .. B*N-1
    int o    = gt & 7;
    int b    = pair >> 10;
    int j    = pair & 1023;

    const float* vrow = V + (size_t)pair * FV_;

    float s1 = 0.f, s2 = 0.f;
    #pragma unroll
    for (int f = 0; f < FV_; f += 4) {
        f32x4 x = *reinterpret_cast<const f32x4*>(vrow + f);
        s1 += x.x * wv[0][o][f]     + x.y * wv[0][o][f + 1]
            + x.z * wv[0][o][f + 2] + x.w * wv[0][o][f + 3];
        s2 += x.x * wv[1][o][f]     + x.y * wv[1][o][f + 1]
            + x.z * wv[1][o][f + 2] + x.w * wv[1][o][f + 3];
    }
    tv1[(b * OUT_ + o) * N_ + j] = s1;
    tv2[(size_t)pair * OUT_ + o] = s2;
}

// Kernel 2: one block per (b,i). No LDS/barrier (weights via scalar loads).
// Plain (non-NT) loads/stores — matches the 6.3 TB/s copy-bench configuration.
// out[b,i,o,j] = relu( sum_l A[b,i,l,j]*W[o,l] + tv1[b,o,j] + tv2[b,i,o] + bias[o] )
__global__ __launch_bounds__(256) void graphcnn_main_kernel(
    const float* __restrict__ A, const float* __restrict__ W,
    const float* __restrict__ bias,
    const float* __restrict__ tv1, const float* __restrict__ tv2,
    float* __restrict__ out)
{
    int bi = blockIdx.x;          // b*N + i
    int b  = bi >> 10;
    int t  = threadIdx.x;
    int j  = t * 4;               // 256 threads * 4 = 1024 = N

    const float* arow = A + (size_t)bi * (L_ * N_);
    const float* tv1b = tv1 + b * OUT_ * N_;
    float* orow = out + (size_t)bi * (OUT_ * N_);

    // 8 streaming A loads, hoisted: needed by every o.
    f32x4 a[L_];
    #pragma unroll
    for (int l = 0; l < L_; ++l)
        a[l] = *reinterpret_cast<const f32x4*>(arow + l * N_ + j);

    #pragma unroll
    for (int o = 0; o < OUT_; ++o) {
        // Wave-uniform scalar values (SGPR): bias[o] + tv2[bi*8+o]
        float bo = bias[o] + tv2[(size_t)bi * OUT_ + o];
        f32x4 r = *reinterpret_cast<const f32x4*>(tv1b + o * N_ + j);
        r.x += bo; r.y += bo; r.z += bo; r.w += bo;
        #pragma unroll
        for (int l = 0; l < L_; ++l) {
            float w = W[o * INFEAT_ + l];   // wave-uniform -> SGPR
            r.x = fmaf(a[l].x, w, r.x);
            r.y = fmaf(a[l].y, w, r.y);
            r.z = fmaf(a[l].z, w, r.z);
            r.w = fmaf(a[l].w, w, r.w);
        }
        r.x = fmaxf(r.x, 0.f);
        r.y = fmaxf(r.y, 0.f);
        r.z = fmaxf(r.z, 0.f);
        r.w = fmaxf(r.w, 0.f);
        *reinterpret_cast<f32x4*>(orow + o * N_ + j) = r;
    }
}

extern "C" void kernel_launch(void* const* d_in, const int* in_sizes, int n_in,
                              void* d_out, int out_size, void* d_ws, size_t ws_size,
                              hipStream_t stream) {
    const float* A    = (const float*)d_in[0];
    const float* V    = (const float*)d_in[1];
    const float* W    = (const float*)d_in[2];
    const float* bias = (const float*)d_in[3];
    float* out = (float*)d_out;

    float* tv1 = (float*)d_ws;                    // B*OUT*N floats = 32768
    float* tv2 = tv1 + (size_t)B_ * OUT_ * N_;    // B*N*OUT floats = 32768

    precompute_tv_kernel<<<(B_ * N_ * OUT_) / 256, 256, 0, stream>>>(V, W, tv1, tv2);
    graphcnn_main_kernel<<<B_ * N_, 256, 0, stream>>>(A, W, bias, tv1, tv2, out);
}